// Round 1
// baseline (176.506 us; speedup 1.0000x reference)
//
#include <hip/hip_runtime.h>

#define NN 8192
#define DIN 7
#define DH 8
#define DOUT 23
#define CUTOFF 3.6f
#define SLOPE 0.01f

__device__ __forceinline__ float leaky(float v) { return v >= 0.0f ? v : SLOPE * v; }

// ---------------- K1: per-node MLP -> coords+s, vals; zero accum; block max(s) ----------
__global__ __launch_bounds__(256) void k1_node(
    const float* __restrict__ x,
    const float* __restrict__ W1, const float* __restrict__ b1,
    const float* __restrict__ W2, const float* __restrict__ b2,
    const float* __restrict__ W3, const float* __restrict__ b3,
    float4* __restrict__ ce, float4* __restrict__ p,
    float* __restrict__ accum, float* __restrict__ pmax)
{
    int tid = threadIdx.x;
    int n = blockIdx.x * 256 + tid;

    float xi[DIN];
#pragma unroll
    for (int d = 0; d < DIN; ++d) xi[d] = x[n * DIN + d];

    float h1[DH];
#pragma unroll
    for (int k = 0; k < DH; ++k) {
        float t = b1[k];
#pragma unroll
        for (int d = 0; d < DIN; ++d) t = fmaf(W1[k * DIN + d], xi[d], t);
        h1[k] = leaky(t);
    }
    float h2[DH];
#pragma unroll
    for (int k = 0; k < DH; ++k) {
        float t = b2[k];
#pragma unroll
        for (int d = 0; d < DH; ++d) t = fmaf(W2[k * DH + d], h1[d], t);
        h2[k] = leaky(t);
    }
    float h3[DOUT];
#pragma unroll
    for (int m = 0; m < DOUT; ++m) {
        float t = b3[m];
#pragma unroll
        for (int d = 0; d < DH; ++d) t = fmaf(W3[m * DH + d], h2[d], t);
        h3[m] = t;
    }
    float s = 0.0f;
#pragma unroll
    for (int k = 0; k < 8; ++k) s = fmaf(h3[7 + k], h3[15 + k], s);

    ce[n] = make_float4(xi[0], xi[1], xi[2], s);            // s later replaced by E
    p[2 * n]     = make_float4(h3[0], h3[1], h3[2], h3[3]); // vals, later scaled by E
    p[2 * n + 1] = make_float4(h3[4], h3[5], h3[6], 0.0f);

#pragma unroll
    for (int q = 0; q < 8; ++q) accum[(size_t)n * 8 + q] = 0.0f;  // ws is 0xAA-poisoned

    __shared__ float red[256];
    red[tid] = s;
    __syncthreads();
    for (int off = 128; off > 0; off >>= 1) {
        if (tid < off) red[tid] = fmaxf(red[tid], red[tid + off]);
        __syncthreads();
    }
    if (tid == 0) pmax[blockIdx.x] = red[0];
}

// ---------------- K2: global max, E = exp(s - M), scale vals -> P ------------------------
__global__ __launch_bounds__(256) void k2_scale(
    float4* __restrict__ ce, float4* __restrict__ p,
    const float* __restrict__ pmax)
{
    __shared__ float sM;
    if (threadIdx.x == 0) {
        float m = pmax[0];
#pragma unroll
        for (int i = 1; i < 32; ++i) m = fmaxf(m, pmax[i]);
        sM = m;
    }
    __syncthreads();
    int n = blockIdx.x * 256 + threadIdx.x;
    float4 c = ce[n];
    float E = expf(c.w - sM);
    c.w = E;
    ce[n] = c;
    float4 p0 = p[2 * n], p1 = p[2 * n + 1];
    p0.x *= E; p0.y *= E; p0.z *= E; p0.w *= E;
    p1.x *= E; p1.y *= E; p1.z *= E; p1.w = 0.0f;
    p[2 * n] = p0;
    p[2 * n + 1] = p1;
}

// ---------------- K3: O(N^2) masked accumulation -----------------------------------------
// grid (16, 32): blockIdx.x -> 512 rows (2 per thread), blockIdx.y -> 256-wide j chunk.
// j-index is wave-uniform -> ce[j]/p[2j]/p[2j+1] loads should lower to s_load_dwordx4.
__global__ __launch_bounds__(256) void k3_attn(
    const float4* __restrict__ ce, const float4* __restrict__ p,
    float* __restrict__ accum)
{
    int tid = threadIdx.x;
    int r0 = blockIdx.x * 512 + tid;
    int r1 = r0 + 256;
    int jbase = blockIdx.y * 256;

    float4 c0 = ce[r0];
    float4 c1 = ce[r1];

    float d0 = 0.0f, d1 = 0.0f;
    float a0[7], a1[7];
#pragma unroll
    for (int q = 0; q < 7; ++q) { a0[q] = 0.0f; a1[q] = 0.0f; }

#pragma unroll 4
    for (int jj = 0; jj < 256; ++jj) {
        int j = jbase + jj;
        float4 cj = ce[j];
        float4 q0 = p[2 * j];
        float4 q1 = p[2 * j + 1];
        // exact ref order: ((|dx|) + |dy|) + |dz|
        float t0 = fabsf(c0.x - cj.x) + fabsf(c0.y - cj.y) + fabsf(c0.z - cj.z);
        float t1 = fabsf(c1.x - cj.x) + fabsf(c1.y - cj.y) + fabsf(c1.z - cj.z);
        float w0 = (t0 <= CUTOFF) ? 1.0f : 0.0f;
        float w1 = (t1 <= CUTOFF) ? 1.0f : 0.0f;
        d0 = fmaf(w0, cj.w, d0);
        d1 = fmaf(w1, cj.w, d1);
        a0[0] = fmaf(w0, q0.x, a0[0]);  a1[0] = fmaf(w1, q0.x, a1[0]);
        a0[1] = fmaf(w0, q0.y, a0[1]);  a1[1] = fmaf(w1, q0.y, a1[1]);
        a0[2] = fmaf(w0, q0.z, a0[2]);  a1[2] = fmaf(w1, q0.z, a1[2]);
        a0[3] = fmaf(w0, q0.w, a0[3]);  a1[3] = fmaf(w1, q0.w, a1[3]);
        a0[4] = fmaf(w0, q1.x, a0[4]);  a1[4] = fmaf(w1, q1.x, a1[4]);
        a0[5] = fmaf(w0, q1.y, a0[5]);  a1[5] = fmaf(w1, q1.y, a1[5]);
        a0[6] = fmaf(w0, q1.z, a0[6]);  a1[6] = fmaf(w1, q1.z, a1[6]);
    }

    float* A0 = accum + (size_t)r0 * 8;
    atomicAdd(A0 + 0, d0);
#pragma unroll
    for (int q = 0; q < 7; ++q) atomicAdd(A0 + 1 + q, a0[q]);
    float* A1 = accum + (size_t)r1 * 8;
    atomicAdd(A1 + 0, d1);
#pragma unroll
    for (int q = 0; q < 7; ++q) atomicAdd(A1 + 1 + q, a1[q]);
}

// ---------------- K4: subtract self, normalize, encoder/decoder MLP, write out ------------
__global__ __launch_bounds__(256) void k4_final(
    const float* __restrict__ x,
    const float* __restrict__ We, const float* __restrict__ be,
    const float* __restrict__ Wd, const float* __restrict__ bd,
    const float4* __restrict__ ce, const float4* __restrict__ p,
    const float* __restrict__ accum, float* __restrict__ out)
{
    int n = blockIdx.x * 256 + threadIdx.x;
    float4 c  = ce[n];
    float4 p0 = p[2 * n], p1 = p[2 * n + 1];
    const float* A = accum + (size_t)n * 8;

    float denom = A[0] - c.w;                 // remove diagonal (always within cutoff)
    float agg[7];
    agg[0] = A[1] - p0.x;
    agg[1] = A[2] - p0.y;
    agg[2] = A[3] - p0.z;
    agg[3] = A[4] - p0.w;
    agg[4] = A[5] - p1.x;
    agg[5] = A[6] - p1.y;
    agg[6] = A[7] - p1.z;
    denom = fmaxf(denom, 1e-30f);
    float inv = 1.0f / denom;

    float inp[14];
#pragma unroll
    for (int d = 0; d < DIN; ++d) inp[d] = x[n * DIN + d];
#pragma unroll
    for (int q = 0; q < 7; ++q) inp[7 + q] = agg[q] * inv;

    float codes[DH];
#pragma unroll
    for (int k = 0; k < DH; ++k) {
        float t = be[k];
#pragma unroll
        for (int d = 0; d < 14; ++d) t = fmaf(We[k * 14 + d], inp[d], t);
        codes[k] = leaky(t);
    }
#pragma unroll
    for (int cc = 0; cc < DIN; ++cc) {
        float t = bd[cc];
#pragma unroll
        for (int k = 0; k < DH; ++k) t = fmaf(Wd[cc * DH + k], codes[k], t);
        out[(size_t)n * DIN + cc] = t;
    }
}

extern "C" void kernel_launch(void* const* d_in, const int* in_sizes, int n_in,
                              void* d_out, int out_size, void* d_ws, size_t ws_size,
                              hipStream_t stream) {
    const float* x  = (const float*)d_in[0];
    const float* W1 = (const float*)d_in[1];
    const float* b1 = (const float*)d_in[2];
    const float* W2 = (const float*)d_in[3];
    const float* b2 = (const float*)d_in[4];
    const float* W3 = (const float*)d_in[5];
    const float* b3 = (const float*)d_in[6];
    const float* We = (const float*)d_in[7];
    const float* be = (const float*)d_in[8];
    const float* Wd = (const float*)d_in[9];
    const float* bd = (const float*)d_in[10];
    float* out = (float*)d_out;

    char* ws = (char*)d_ws;
    float4* ce    = (float4*)ws;                              // 8192*16  = 131072 B
    float4* p     = (float4*)(ws + 131072);                   // 16384*16 = 262144 B
    float*  accum = (float*)(ws + 131072 + 262144);           // 65536*4  = 262144 B
    float*  pmax  = (float*)(ws + 131072 + 262144 + 262144);  // 32*4     = 128 B

    k1_node<<<32, 256, 0, stream>>>(x, W1, b1, W2, b2, W3, b3, ce, p, accum, pmax);
    k2_scale<<<32, 256, 0, stream>>>(ce, p, pmax);
    dim3 g3(16, 32);
    k3_attn<<<g3, 256, 0, stream>>>(ce, p, accum);
    k4_final<<<32, 256, 0, stream>>>(x, We, be, Wd, bd, ce, p, accum, out);
}

// Round 2
// 117.716 us; speedup vs baseline: 1.4994x; 1.4994x over previous
//
#include <hip/hip_runtime.h>

#define NN 8192
#define DIN 7
#define DH 8
#define DOUT 23
#define CUTOFF 3.6f
#define SLOPE 0.01f
#define CHUNK 256           // j-chunk per k3 block
#define NCHUNK (NN / CHUNK) // 32

__device__ __forceinline__ float leaky(float v) { return v >= 0.0f ? v : SLOPE * v; }

// ---------------- K1: per-node MLP -> ce(coords,s), p(raw vals); zero accum; block max(s)
__global__ __launch_bounds__(256) void k1_node(
    const float* __restrict__ x,
    const float* __restrict__ W1, const float* __restrict__ b1,
    const float* __restrict__ W2, const float* __restrict__ b2,
    const float* __restrict__ W3, const float* __restrict__ b3,
    float4* __restrict__ ce, float4* __restrict__ p,
    float* __restrict__ accum, float* __restrict__ pmax)
{
    int tid = threadIdx.x;
    int n = blockIdx.x * 256 + tid;

    float xi[DIN];
#pragma unroll
    for (int d = 0; d < DIN; ++d) xi[d] = x[n * DIN + d];

    float h1[DH];
#pragma unroll
    for (int k = 0; k < DH; ++k) {
        float t = b1[k];
#pragma unroll
        for (int d = 0; d < DIN; ++d) t = fmaf(W1[k * DIN + d], xi[d], t);
        h1[k] = leaky(t);
    }
    float h2[DH];
#pragma unroll
    for (int k = 0; k < DH; ++k) {
        float t = b2[k];
#pragma unroll
        for (int d = 0; d < DH; ++d) t = fmaf(W2[k * DH + d], h1[d], t);
        h2[k] = leaky(t);
    }
    float h3[DOUT];
#pragma unroll
    for (int m = 0; m < DOUT; ++m) {
        float t = b3[m];
#pragma unroll
        for (int d = 0; d < DH; ++d) t = fmaf(W3[m * DH + d], h2[d], t);
        h3[m] = t;
    }
    float s = 0.0f;
#pragma unroll
    for (int k = 0; k < 8; ++k) s = fmaf(h3[7 + k], h3[15 + k], s);

    ce[n] = make_float4(xi[0], xi[1], xi[2], s);            // raw s; E computed in k3/k4
    p[2 * n]     = make_float4(h3[0], h3[1], h3[2], h3[3]); // raw vals
    p[2 * n + 1] = make_float4(h3[4], h3[5], h3[6], 0.0f);

    // zero accumulator (transposed layout [q][row]); ws is 0xAA-poisoned
#pragma unroll
    for (int q = 0; q < 8; ++q) accum[q * NN + n] = 0.0f;

    __shared__ float red[256];
    red[tid] = s;
    __syncthreads();
    for (int off = 128; off > 0; off >>= 1) {
        if (tid < off) red[tid] = fmaxf(red[tid], red[tid + off]);
        __syncthreads();
    }
    if (tid == 0) pmax[blockIdx.x] = red[0];
}

// ---------------- K3: O(N^2) masked accumulation, LDS-staged j chunk ---------------------
// grid (32, 32): blockIdx.x -> 256 rows (1/thread), blockIdx.y -> 256-wide j chunk.
__global__ __launch_bounds__(256) void k3_attn(
    const float4* __restrict__ ce, const float4* __restrict__ p,
    const float* __restrict__ pmax, float* __restrict__ accum)
{
    __shared__ float4 sA[CHUNK];   // cx, cy, cz, E
    __shared__ float4 sB[CHUNK];   // E*vals[0..3]
    __shared__ float4 sC[CHUNK];   // E*vals[4..6], 0
    __shared__ float sMred[32];

    int tid = threadIdx.x;
    if (tid < 32) sMred[tid] = pmax[tid];
    __syncthreads();
    float M = sMred[0];
#pragma unroll
    for (int i = 1; i < 32; ++i) M = fmaxf(M, sMred[i]);

    // stage chunk: compute E and scaled vals on the fly
    int j = blockIdx.y * CHUNK + tid;
    {
        float4 c  = ce[j];
        float4 p0 = p[2 * j], p1 = p[2 * j + 1];
        float E = expf(c.w - M);
        sA[tid] = make_float4(c.x, c.y, c.z, E);
        sB[tid] = make_float4(p0.x * E, p0.y * E, p0.z * E, p0.w * E);
        sC[tid] = make_float4(p1.x * E, p1.y * E, p1.z * E, 0.0f);
    }
    __syncthreads();

    int r = blockIdx.x * 256 + tid;
    float4 c0 = ce[r];

    float d0 = 0.0f;
    float a[7];
#pragma unroll
    for (int q = 0; q < 7; ++q) a[q] = 0.0f;

#pragma unroll 8
    for (int jj = 0; jj < CHUNK; ++jj) {
        float4 cj = sA[jj];
        float4 q0 = sB[jj];
        float4 q1 = sC[jj];
        // exact ref order: (|dx| + |dy|) + |dz|
        float t = fabsf(c0.x - cj.x) + fabsf(c0.y - cj.y) + fabsf(c0.z - cj.z);
        float w = (t <= CUTOFF) ? 1.0f : 0.0f;
        d0  = fmaf(w, cj.w, d0);
        a[0] = fmaf(w, q0.x, a[0]);
        a[1] = fmaf(w, q0.y, a[1]);
        a[2] = fmaf(w, q0.z, a[2]);
        a[3] = fmaf(w, q0.w, a[3]);
        a[4] = fmaf(w, q1.x, a[4]);
        a[5] = fmaf(w, q1.y, a[5]);
        a[6] = fmaf(w, q1.z, a[6]);
    }

    // transposed accum: each atomic instr -> 256 contiguous bytes (4 cachelines)
    atomicAdd(&accum[0 * NN + r], d0);
#pragma unroll
    for (int q = 0; q < 7; ++q) atomicAdd(&accum[(q + 1) * NN + r], a[q]);
}

// ---------------- K4: subtract self, normalize, encoder/decoder MLP, write out ------------
__global__ __launch_bounds__(256) void k4_final(
    const float* __restrict__ x,
    const float* __restrict__ We, const float* __restrict__ be,
    const float* __restrict__ Wd, const float* __restrict__ bd,
    const float4* __restrict__ ce, const float4* __restrict__ p,
    const float* __restrict__ pmax,
    const float* __restrict__ accum, float* __restrict__ out)
{
    float M = pmax[0];
#pragma unroll
    for (int i = 1; i < 32; ++i) M = fmaxf(M, pmax[i]);

    int n = blockIdx.x * 256 + threadIdx.x;
    float4 c  = ce[n];
    float4 p0 = p[2 * n], p1 = p[2 * n + 1];
    float E = expf(c.w - M);

    float denom = accum[0 * NN + n] - E;      // remove diagonal (always within cutoff)
    float agg[7];
    agg[0] = accum[1 * NN + n] - E * p0.x;
    agg[1] = accum[2 * NN + n] - E * p0.y;
    agg[2] = accum[3 * NN + n] - E * p0.z;
    agg[3] = accum[4 * NN + n] - E * p0.w;
    agg[4] = accum[5 * NN + n] - E * p1.x;
    agg[5] = accum[6 * NN + n] - E * p1.y;
    agg[6] = accum[7 * NN + n] - E * p1.z;
    denom = fmaxf(denom, 1e-30f);
    float inv = 1.0f / denom;

    float inp[14];
#pragma unroll
    for (int d = 0; d < DIN; ++d) inp[d] = x[n * DIN + d];
#pragma unroll
    for (int q = 0; q < 7; ++q) inp[7 + q] = agg[q] * inv;

    float codes[DH];
#pragma unroll
    for (int k = 0; k < DH; ++k) {
        float t = be[k];
#pragma unroll
        for (int d = 0; d < 14; ++d) t = fmaf(We[k * 14 + d], inp[d], t);
        codes[k] = leaky(t);
    }
#pragma unroll
    for (int cc = 0; cc < DIN; ++cc) {
        float t = bd[cc];
#pragma unroll
        for (int k = 0; k < DH; ++k) t = fmaf(Wd[cc * DH + k], codes[k], t);
        out[(size_t)n * DIN + cc] = t;
    }
}

extern "C" void kernel_launch(void* const* d_in, const int* in_sizes, int n_in,
                              void* d_out, int out_size, void* d_ws, size_t ws_size,
                              hipStream_t stream) {
    const float* x  = (const float*)d_in[0];
    const float* W1 = (const float*)d_in[1];
    const float* b1 = (const float*)d_in[2];
    const float* W2 = (const float*)d_in[3];
    const float* b2 = (const float*)d_in[4];
    const float* W3 = (const float*)d_in[5];
    const float* b3 = (const float*)d_in[6];
    const float* We = (const float*)d_in[7];
    const float* be = (const float*)d_in[8];
    const float* Wd = (const float*)d_in[9];
    const float* bd = (const float*)d_in[10];
    float* out = (float*)d_out;

    char* ws = (char*)d_ws;
    float4* ce    = (float4*)ws;                              // 8192*16  = 131072 B
    float4* p     = (float4*)(ws + 131072);                   // 16384*16 = 262144 B
    float*  accum = (float*)(ws + 131072 + 262144);           // 65536*4  = 262144 B
    float*  pmax  = (float*)(ws + 131072 + 262144 + 262144);  // 32*4     = 128 B

    k1_node<<<32, 256, 0, stream>>>(x, W1, b1, W2, b2, W3, b3, ce, p, accum, pmax);
    dim3 g3(32, NCHUNK);
    k3_attn<<<g3, 256, 0, stream>>>(ce, p, pmax, accum);
    k4_final<<<32, 256, 0, stream>>>(x, We, be, Wd, bd, ce, p, pmax, accum, out);
}